// Round 5
// baseline (95.364 us; speedup 1.0000x reference)
//
#include <hip/hip_runtime.h>
#include <hip/hip_bf16.h>

#define IN_DIM  1024
#define OUT_DIM 1024
#define HID     4
#define BATCH   8192
#define NCOL    (OUT_DIM * HID)   // 4096 = GEMM M dimension (oh), N = 8192 (batch)

typedef __bf16 bf16x8 __attribute__((ext_vector_type(8)));
typedef float  f32x4  __attribute__((ext_vector_type(4)));
typedef float  f32x16 __attribute__((ext_vector_type(16)));

__device__ __forceinline__ unsigned short f2bf(float f) {
  union { float f; unsigned int u; } v; v.f = f;
  unsigned int u = v.u;
  u += 0x7FFFu + ((u >> 16) & 1u);   // round-to-nearest-even
  return (unsigned short)(u >> 16);
}

// ---- x: f32 [8192][1024] -> bf16 [8192][1024] ----
__global__ __launch_bounds__(256) void cvt_x_kernel(const float4* __restrict__ in,
                                                    ushort4* __restrict__ out) {
  int i = blockIdx.x * 256 + threadIdx.x;
  float4 v = in[i];
  ushort4 o;
  o.x = f2bf(v.x); o.y = f2bf(v.y); o.z = f2bf(v.z); o.w = f2bf(v.w);
  out[i] = o;
}

// ---- W1: f32 (O,I,H) -> bf16 W1t[(o*4+h)][i]  (M x K row-major) ----
__global__ __launch_bounds__(256) void cvt_w1t_kernel(const float* __restrict__ W1,
                                                      ushort4* __restrict__ out) {
  int b = blockIdx.x;
  int g = ((b & 7) * ((int)gridDim.x >> 3) + (b >> 3)) * 256 + threadIdx.x;
  int i4 = g & 255;
  int oh = g >> 8;
  int h = oh & 3, o = oh >> 2;
  const float* src = W1 + (size_t)o * 4096 + h;
  ushort4 r;
  r.x = f2bf(src[(i4 * 4 + 0) * 4]);
  r.y = f2bf(src[(i4 * 4 + 1) * 4]);
  r.z = f2bf(src[(i4 * 4 + 2) * 4]);
  r.w = f2bf(src[(i4 * 4 + 3) * 4]);
  out[(size_t)oh * 256 + i4] = r;
}

__device__ __forceinline__ void gload16(const void* g, void* l) {
  __builtin_amdgcn_global_load_lds(
      (const __attribute__((address_space(1))) unsigned int*)g,
      (__attribute__((address_space(3))) unsigned int*)l, 16, 0, 0);
}

// ===== transposed GEMM: C[oh][batch] = W1t x xbf^T, tile 256Mx128N, BK=32 ====
// 4 waves 2(M)x2(N); per-wave 128x64 via 32x32x16 MFMA: acc[4][2] f32x16.
// LDS 72 KiB = 3 rotating bufs x (A[256][32] + B[128][32]) bf16 -> 2 blocks/CU.
// Prefetch depth 2: iter kt stages kt+2; vmcnt(6) = stage kt+1 complete.
// Swizzle: 16B slot phys = log ^ ((row>>1)&3)  [R4's (row&3) was 4-way
// conflicted per quarter-wave: parity-correlated]. Staged via inverse-
// swizzled global col (linear LDS dest), read with same XOR.
// No manual lgkmcnt: reads ordered ks0->ks1, compiler emits fine-grained
// per-operand waits (m97 behavior) -> intra-wave read/MFMA overlap.
__global__ __launch_bounds__(256, 2) void mlp_gemm_kernel(
    const unsigned short* __restrict__ A,   // w1t [4096][1024]  (M = oh)
    const unsigned short* __restrict__ Bm,  // xbf [8192][1024]  (N = batch)
    const f32x4* __restrict__ b1v,          // [1024] float4 per o
    const f32x4* __restrict__ w2v,          // [1024] float4 per o
    const float* __restrict__ b2,           // [1024]
    float* __restrict__ out) {              // [8192][1024]
  __shared__ __align__(16) unsigned short lds[36864];   // 72 KiB

  const int bid = blockIdx.x;
  const int xcd = bid & 7, loc = bid >> 3;        // 128 blocks per XCD
  const int bm = loc >> 3;                        // oh tile 0..15 (bn-inner)
  const int bn = xcd * 8 + (loc & 7);             // batch tile 0..63
  const int tileM = bm * 256, tileN = bn * 128;

  const int t = threadIdx.x;
  const int lane = t & 63, wid = t >> 6;
  const int wm = wid >> 1, wn = wid & 1;
  const int l31 = lane & 31, hi = lane >> 5;

  // staging: thread t -> rows sr+{0,64,128,192}(A), sr+{0,64}(B); slot t&3
  const int sr = t >> 2;
  const int sc = (((t & 3) ^ ((sr >> 1) & 3)) << 3);   // inverse-swizzled col
  const unsigned short* Abase = A  + (size_t)(tileM + sr) * IN_DIM + sc;
  const unsigned short* Bbase = Bm + (size_t)(tileN + sr) * IN_DIM + sc;

  auto stage = [&](int kt, int p) {               // 6 x gload16 = 24 KB
    const int kb = kt * 32;
    unsigned short* lA = lds + p * 12288 + t * 8;
#pragma unroll
    for (int i = 0; i < 4; ++i)
      gload16(Abase + (size_t)i * 64 * IN_DIM + kb, lA + i * 2048);
#pragma unroll
    for (int i = 0; i < 2; ++i)
      gload16(Bbase + (size_t)i * 64 * IN_DIM + kb, lA + 8192 + i * 2048);
  };

  f32x16 acc[4][2];
#pragma unroll
  for (int m = 0; m < 4; ++m)
#pragma unroll
    for (int n = 0; n < 2; ++n)
#pragma unroll
      for (int r = 0; r < 16; ++r) acc[m][n][r] = 0.f;

  // fragment addressing (elems): row*32 + phys*8; phys = (ks*2+hi)^swz
  const int swz = (l31 >> 1) & 3;
  const int p0 = (hi ^ swz) * 8;         // ks=0
  const int p1 = ((2 + hi) ^ swz) * 8;   // ks=1
  const int arow = (wm * 128 + l31) * 32;          // + mf*1024
  const int brow = 8192 + (wn * 64 + l31) * 32;    // + nf*1024

  stage(0, 0);
  stage(1, 1);
  asm volatile("s_waitcnt vmcnt(6)" ::: "memory");   // stage(0) complete
  __builtin_amdgcn_s_barrier();
  __builtin_amdgcn_sched_barrier(0);

  // mode 0: stage kt+2, end vmcnt(6); 1: no stage, end vmcnt(0); 2: tail
  auto ktile = [&](int kt, int pr, int ps, int mode) {
    if (mode == 0) stage(kt + 2, ps);
    const unsigned short* bufp = lds + pr * 12288;
    bf16x8 a0[4], b0[2], a1[4], b1_[2];
    // ks0 reads, first-MFMA operands first
    a0[0] = *(const bf16x8*)(bufp + arow + 0 * 1024 + p0);
    b0[0] = *(const bf16x8*)(bufp + brow + 0 * 1024 + p0);
    b0[1] = *(const bf16x8*)(bufp + brow + 1 * 1024 + p0);
    a0[1] = *(const bf16x8*)(bufp + arow + 1 * 1024 + p0);
    a0[2] = *(const bf16x8*)(bufp + arow + 2 * 1024 + p0);
    a0[3] = *(const bf16x8*)(bufp + arow + 3 * 1024 + p0);
    // ks1 reads
    a1[0] = *(const bf16x8*)(bufp + arow + 0 * 1024 + p1);
    b1_[0] = *(const bf16x8*)(bufp + brow + 0 * 1024 + p1);
    b1_[1] = *(const bf16x8*)(bufp + brow + 1 * 1024 + p1);
    a1[1] = *(const bf16x8*)(bufp + arow + 1 * 1024 + p1);
    a1[2] = *(const bf16x8*)(bufp + arow + 2 * 1024 + p1);
    a1[3] = *(const bf16x8*)(bufp + arow + 3 * 1024 + p1);
    // MFMA: compiler inserts fine-grained lgkmcnt per operand
#pragma unroll
    for (int mf = 0; mf < 4; ++mf)
#pragma unroll
      for (int nf = 0; nf < 2; ++nf)
        acc[mf][nf] = __builtin_amdgcn_mfma_f32_32x32x16_bf16(a0[mf], b0[nf], acc[mf][nf], 0, 0, 0);
#pragma unroll
    for (int mf = 0; mf < 4; ++mf)
#pragma unroll
      for (int nf = 0; nf < 2; ++nf)
        acc[mf][nf] = __builtin_amdgcn_mfma_f32_32x32x16_bf16(a1[mf], b1_[nf], acc[mf][nf], 0, 0, 0);
    if (mode == 0)      asm volatile("s_waitcnt vmcnt(6)" ::: "memory");
    else if (mode == 1) asm volatile("s_waitcnt vmcnt(0)" ::: "memory");
    if (mode < 2) {
      __builtin_amdgcn_s_barrier();
      __builtin_amdgcn_sched_barrier(0);
    }
  };

  for (int g = 0; g < 30; g += 3) {   // read buf rotates 0,1,2; stage +2
    ktile(g,     0, 2, 0);
    ktile(g + 1, 1, 0, 0);
    ktile(g + 2, 2, 1, 0);
  }
  ktile(30, 0, 0, 1);
  ktile(31, 1, 0, 2);
  __syncthreads();

  // ---- fused epilogue: in-register hidden-dot ----
  // C/D (32x32): col = lane&31 = batch_local, row = (reg&3)+8*(reg>>2)+4*hi.
  // oh = wm*128 + mf*32 + row  ->  h = reg&3, o_loc = wm*32 + mf*8 + 2*(reg>>2) + hi.
  float* LE = (float*)lds;                        // [128 batch][65] f32
  const int obase = tileM >> 2;                   // block's 64 o-values
#pragma unroll
  for (int mf = 0; mf < 4; ++mf) {
#pragma unroll
    for (int g = 0; g < 4; ++g) {
      int o_loc = wm * 32 + mf * 8 + 2 * g + hi;
      f32x4 b1q = b1v[obase + o_loc];
      f32x4 w2q = w2v[obase + o_loc];
#pragma unroll
      for (int nf = 0; nf < 2; ++nf) {
        int bat = wn * 64 + nf * 32 + l31;
        float v = 0.f;
#pragma unroll
        for (int h = 0; h < 4; ++h) {
          float hj = acc[mf][nf][4 * g + h] + b1q[h];
          hj = (hj >= 0.f) ? hj : 0.1f * hj;      // LeakyReLU(0.1)
          v += hj * w2q[h];
        }
        LE[bat * 65 + o_loc] = v;                 // banks bat+o_loc: 2-way max
      }
    }
  }
  __syncthreads();

  const int col = t & 63, rowb = t >> 6;
  const float b2s = b2[obase + col];
  float* outB = out + (size_t)tileN * OUT_DIM + obase;
#pragma unroll
  for (int i = 0; i < 32; ++i) {
    int row = rowb + i * 4;
    outB[(size_t)row * OUT_DIM + col] = LE[row * 65 + col] + b2s;
  }
}

// ---- safety fallback (pure f32, used only if d_ws is too small) ----
__global__ __launch_bounds__(256) void fallback_kernel(
    const float* __restrict__ x, const float* __restrict__ W1,
    const float* __restrict__ b1, const float* __restrict__ W2,
    const float* __restrict__ b2, float* __restrict__ out) {
  int idx = blockIdx.x * 256 + threadIdx.x;
  if (idx >= BATCH * OUT_DIM) return;
  int bb = idx >> 10, o = idx & 1023;
  const float4* w1p = (const float4*)(W1 + (size_t)o * 4096);
  const float*  xp  = x + (size_t)bb * 1024;
  float4 acc = *(const float4*)(b1 + o * 4);
  for (int i = 0; i < 1024; ++i) {
    float xv = xp[i];
    float4 w = w1p[i];
    acc.x += xv * w.x; acc.y += xv * w.y; acc.z += xv * w.z; acc.w += xv * w.w;
  }
  float4 w2 = *(const float4*)(W2 + o * 4);
  float r = b2[o];
  r += ((acc.x >= 0.f) ? acc.x : 0.1f * acc.x) * w2.x;
  r += ((acc.y >= 0.f) ? acc.y : 0.1f * acc.y) * w2.y;
  r += ((acc.z >= 0.f) ? acc.z : 0.1f * acc.z) * w2.z;
  r += ((acc.w >= 0.f) ? acc.w : 0.1f * acc.w) * w2.w;
  out[(size_t)bb * OUT_DIM + o] = r;
}

extern "C" void kernel_launch(void* const* d_in, const int* in_sizes, int n_in,
                              void* d_out, int out_size, void* d_ws, size_t ws_size,
                              hipStream_t stream) {
  const float* x  = (const float*)d_in[0];
  const float* W1 = (const float*)d_in[1];
  const float* b1 = (const float*)d_in[2];
  const float* W2 = (const float*)d_in[3];
  const float* b2 = (const float*)d_in[4];
  float* out = (float*)d_out;

  size_t need = (size_t)BATCH * IN_DIM * 2 + (size_t)NCOL * IN_DIM * 2;  // 25.2 MB
  if (ws_size >= need) {
    unsigned short* xbf = (unsigned short*)d_ws;
    unsigned short* w1t = xbf + (size_t)BATCH * IN_DIM;
    cvt_x_kernel<<<(BATCH * IN_DIM / 4) / 256, 256, 0, stream>>>((const float4*)x, (ushort4*)xbf);
    cvt_w1t_kernel<<<(NCOL * IN_DIM / 4) / 256, 256, 0, stream>>>(W1, (ushort4*)w1t);
    mlp_gemm_kernel<<<(NCOL / 256) * (BATCH / 128), 256, 0, stream>>>(
        w1t, xbf, (const f32x4*)b1, (const f32x4*)W2, b2, out);
  } else {
    fallback_kernel<<<(BATCH * OUT_DIM + 255) / 256, 256, 0, stream>>>(x, W1, b1, W2, b2, out);
  }
}

// Round 6
// 92.808 us; speedup vs baseline: 1.0275x; 1.0275x over previous
//
#include <hip/hip_runtime.h>
#include <hip/hip_bf16.h>

#define IN_DIM  1024
#define OUT_DIM 1024
#define HID     4
#define BATCH   8192
#define NCOL    (OUT_DIM * HID)   // 4096 = GEMM M dimension (oh), N = 8192 (batch)

typedef __bf16 bf16x8 __attribute__((ext_vector_type(8)));
typedef float  f32x4  __attribute__((ext_vector_type(4)));
typedef float  f32x16 __attribute__((ext_vector_type(16)));

__device__ __forceinline__ unsigned short f2bf(float f) {
  union { float f; unsigned int u; } v; v.f = f;
  unsigned int u = v.u;
  u += 0x7FFFu + ((u >> 16) & 1u);   // round-to-nearest-even
  return (unsigned short)(u >> 16);
}

// ---- x: f32 [8192][1024] -> bf16 [8192][1024] ----
__global__ __launch_bounds__(256) void cvt_x_kernel(const float4* __restrict__ in,
                                                    ushort4* __restrict__ out) {
  int i = blockIdx.x * 256 + threadIdx.x;
  float4 v = in[i];
  ushort4 o;
  o.x = f2bf(v.x); o.y = f2bf(v.y); o.z = f2bf(v.z); o.w = f2bf(v.w);
  out[i] = o;
}

// ---- W1: f32 (O,I,H) -> bf16 W1t[(o*4+h)][i]  (M x K row-major) ----
__global__ __launch_bounds__(256) void cvt_w1t_kernel(const float* __restrict__ W1,
                                                      ushort4* __restrict__ out) {
  int b = blockIdx.x;
  int g = ((b & 7) * ((int)gridDim.x >> 3) + (b >> 3)) * 256 + threadIdx.x;
  int i4 = g & 255;
  int oh = g >> 8;
  int h = oh & 3, o = oh >> 2;
  const float* src = W1 + (size_t)o * 4096 + h;
  ushort4 r;
  r.x = f2bf(src[(i4 * 4 + 0) * 4]);
  r.y = f2bf(src[(i4 * 4 + 1) * 4]);
  r.z = f2bf(src[(i4 * 4 + 2) * 4]);
  r.w = f2bf(src[(i4 * 4 + 3) * 4]);
  out[(size_t)oh * 256 + i4] = r;
}

__device__ __forceinline__ void gload16(const void* g, void* l) {
  __builtin_amdgcn_global_load_lds(
      (const __attribute__((address_space(1))) unsigned int*)g,
      (__attribute__((address_space(3))) unsigned int*)l, 16, 0, 0);
}

// ===== transposed GEMM: C[oh][batch] = W1t x xbf^T, tile 256x256, BK=64 =====
// 4 waves 2(M)x2(N); per-wave 128x128 via 32x32x16 MFMA: acc[4][4] f32x16
// (256 AGPR — unified file). LDS 128 KiB = 2 bufs x (A[256][64]+B[256][64]).
// LDS traffic per block-kt: reads 128 KB + writes 64 KB ~= 1500-1900 cy vs
// MFMA 2048 cy -> MFMA-limited (R5 was 864 cy LDS vs 256 cy MFMA).
// 128B rows (8 slots) + phys = slot ^ (row&7) swizzle = R3-proven ~0 conflicts.
// Depth-1 prefetch: stage(kt+1) first, 2048 cy of MFMA hides the latency,
// vmcnt(0)+barrier once per kt.
__global__ __launch_bounds__(256, 1) void mlp_gemm_kernel(
    const unsigned short* __restrict__ A,   // w1t [4096][1024]  (M = oh)
    const unsigned short* __restrict__ Bm,  // xbf [8192][1024]  (N = batch)
    const f32x4* __restrict__ b1v,          // [1024] float4 per o
    const f32x4* __restrict__ w2v,          // [1024] float4 per o
    const float* __restrict__ b2,           // [1024]
    float* __restrict__ out) {              // [8192][1024]
  __shared__ __align__(16) unsigned short lds[65536];   // 128 KiB

  const int bid = blockIdx.x;                     // 512 blocks
  const int xcd = bid & 7, loc = bid >> 3;        // 64 blocks per XCD
  const int bn = xcd * 4 + (loc & 3);             // batch tile 0..31 (2MB x-slice L2-pinned)
  const int bm = loc >> 2;                        // oh tile 0..15, bn-inner sweep
  const int tileM = bm * 256, tileN = bn * 256;

  const int t = threadIdx.x;
  const int lane = t & 63, wid = t >> 6;
  const int wm = wid >> 1, wn = wid & 1;
  const int l31 = lane & 31, hi = lane >> 5;

  // staging: thread t, instr i -> row 32*i + (t>>3), 16B slot t&7 (linear dest)
  const int sr8 = t >> 3, slt = t & 7;
  const int scol = ((slt ^ (sr8 & 7)) << 3);      // inverse-swizzled source col
  const unsigned short* Asrc = A  + (size_t)(tileM + sr8) * IN_DIM + scol;
  const unsigned short* Bsrc = Bm + (size_t)(tileN + sr8) * IN_DIM + scol;

  auto stage = [&](int kt, int p) {               // 16 x gload16 = 64 KB
    const int kb = kt * 64;
    unsigned short* lA = lds + p * 32768 + t * 8;
    unsigned short* lB = lA + 16384;
#pragma unroll
    for (int i = 0; i < 8; ++i) {
      gload16(Asrc + (size_t)(32 * i) * IN_DIM + kb, lA + i * 2048);
      gload16(Bsrc + (size_t)(32 * i) * IN_DIM + kb, lB + i * 2048);
    }
  };

  f32x16 acc[4][4];
#pragma unroll
  for (int m = 0; m < 4; ++m)
#pragma unroll
    for (int n = 0; n < 4; ++n)
#pragma unroll
      for (int r = 0; r < 16; ++r) acc[m][n][r] = 0.f;

  const int rsw = l31 & 7;                        // row&7 for all frag rows

  stage(0, 0);
  asm volatile("s_waitcnt vmcnt(0)" ::: "memory");
  __builtin_amdgcn_s_barrier();

  for (int kt = 0; kt < 16; ++kt) {
    const int cur = kt & 1;
    if (kt < 15) stage(kt + 1, cur ^ 1);          // issue prefetch first

    const unsigned short* bufp = lds + cur * 32768;
    const unsigned short* aR = bufp + (wm * 128 + l31) * 64;           // + mf*2048
    const unsigned short* bR = bufp + 16384 + (wn * 128 + l31) * 64;   // + nf*2048

#pragma unroll
    for (int ks = 0; ks < 4; ++ks) {
      const int pk = ((2 * ks + hi) ^ rsw) << 3;  // swizzled 16B slot (elems)
      bf16x8 a[4], b[4];
      a[0] = *(const bf16x8*)(aR + 0 * 2048 + pk);
      b[0] = *(const bf16x8*)(bR + 0 * 2048 + pk);
      b[1] = *(const bf16x8*)(bR + 1 * 2048 + pk);
      b[2] = *(const bf16x8*)(bR + 2 * 2048 + pk);
      b[3] = *(const bf16x8*)(bR + 3 * 2048 + pk);
      a[1] = *(const bf16x8*)(aR + 1 * 2048 + pk);
      a[2] = *(const bf16x8*)(aR + 2 * 2048 + pk);
      a[3] = *(const bf16x8*)(aR + 3 * 2048 + pk);
#pragma unroll
      for (int mf = 0; mf < 4; ++mf)
#pragma unroll
        for (int nf = 0; nf < 4; ++nf)
          acc[mf][nf] = __builtin_amdgcn_mfma_f32_32x32x16_bf16(a[mf], b[nf], acc[mf][nf], 0, 0, 0);
    }

    if (kt < 15) asm volatile("s_waitcnt vmcnt(0)" ::: "memory");
    __builtin_amdgcn_s_barrier();
  }
  __syncthreads();   // all frag reads done -> safe to reuse LDS

  // ---- fused epilogue: in-register hidden-dot ----
  // C/D (32x32): col = lane&31 = batch_local, row32 = (reg&3)+8*(reg>>2)+4*hi.
  // oh_local = wm*128 + mf*32 + row32 -> h = reg&3, o_loc = wm*32+mf*8+2*(reg>>2)+hi.
  float* LE = (float*)lds;                        // [256 batch][65] f32 = 66.5 KB
  const int obase = tileM >> 2;                   // block's 64 o-values
#pragma unroll
  for (int mf = 0; mf < 4; ++mf) {
#pragma unroll
    for (int g = 0; g < 4; ++g) {
      int o_loc = wm * 32 + mf * 8 + 2 * g + hi;
      f32x4 b1q = b1v[obase + o_loc];
      f32x4 w2q = w2v[obase + o_loc];
#pragma unroll
      for (int nf = 0; nf < 4; ++nf) {
        int bat = wn * 128 + nf * 32 + l31;
        float v = 0.f;
#pragma unroll
        for (int h = 0; h < 4; ++h) {
          float hj = acc[mf][nf][4 * g + h] + b1q[h];
          hj = (hj >= 0.f) ? hj : 0.1f * hj;      // LeakyReLU(0.1)
          v += hj * w2q[h];
        }
        LE[bat * 65 + o_loc] = v;                 // bank = bat+o_loc: 2-way max
      }
    }
  }
  __syncthreads();

  // coalesced store: out[tileN..+256)[obase..+64); bank = row+col: 2-way free
  const int col = t & 63, rowb = t >> 6;
  const float b2s = b2[obase + col];
  float* outB = out + (size_t)tileN * OUT_DIM + obase;
#pragma unroll
  for (int i = 0; i < 64; ++i) {
    int row = rowb + i * 4;
    outB[(size_t)row * OUT_DIM + col] = LE[row * 65 + col] + b2s;
  }
}

// ---- safety fallback (pure f32, used only if d_ws is too small) ----
__global__ __launch_bounds__(256) void fallback_kernel(
    const float* __restrict__ x, const float* __restrict__ W1,
    const float* __restrict__ b1, const float* __restrict__ W2,
    const float* __restrict__ b2, float* __restrict__ out) {
  int idx = blockIdx.x * 256 + threadIdx.x;
  if (idx >= BATCH * OUT_DIM) return;
  int bb = idx >> 10, o = idx & 1023;
  const float4* w1p = (const float4*)(W1 + (size_t)o * 4096);
  const float*  xp  = x + (size_t)bb * 1024;
  float4 acc = *(const float4*)(b1 + o * 4);
  for (int i = 0; i < 1024; ++i) {
    float xv = xp[i];
    float4 w = w1p[i];
    acc.x += xv * w.x; acc.y += xv * w.y; acc.z += xv * w.z; acc.w += xv * w.w;
  }
  float4 w2 = *(const float4*)(W2 + o * 4);
  float r = b2[o];
  r += ((acc.x >= 0.f) ? acc.x : 0.1f * acc.x) * w2.x;
  r += ((acc.y >= 0.f) ? acc.y : 0.1f * acc.y) * w2.y;
  r += ((acc.z >= 0.f) ? acc.z : 0.1f * acc.z) * w2.z;
  r += ((acc.w >= 0.f) ? acc.w : 0.1f * acc.w) * w2.w;
  out[(size_t)bb * OUT_DIM + o] = r;
}

extern "C" void kernel_launch(void* const* d_in, const int* in_sizes, int n_in,
                              void* d_out, int out_size, void* d_ws, size_t ws_size,
                              hipStream_t stream) {
  const float* x  = (const float*)d_in[0];
  const float* W1 = (const float*)d_in[1];
  const float* b1 = (const float*)d_in[2];
  const float* W2 = (const float*)d_in[3];
  const float* b2 = (const float*)d_in[4];
  float* out = (float*)d_out;

  size_t need = (size_t)BATCH * IN_DIM * 2 + (size_t)NCOL * IN_DIM * 2;  // 25.2 MB
  if (ws_size >= need) {
    unsigned short* xbf = (unsigned short*)d_ws;
    unsigned short* w1t = xbf + (size_t)BATCH * IN_DIM;
    cvt_x_kernel<<<(BATCH * IN_DIM / 4) / 256, 256, 0, stream>>>((const float4*)x, (ushort4*)xbf);
    cvt_w1t_kernel<<<(NCOL * IN_DIM / 4) / 256, 256, 0, stream>>>(W1, (ushort4*)w1t);
    mlp_gemm_kernel<<<(NCOL / 256) * (BATCH / 256), 256, 0, stream>>>(
        w1t, xbf, (const f32x4*)b1, (const f32x4*)W2, b2, out);
  } else {
    fallback_kernel<<<(BATCH * OUT_DIM + 255) / 256, 256, 0, stream>>>(x, W1, b1, W2, b2, out);
  }
}

// Round 7
// 84.328 us; speedup vs baseline: 1.1309x; 1.1006x over previous
//
#include <hip/hip_runtime.h>
#include <hip/hip_bf16.h>

#define IN_DIM  1024
#define OUT_DIM 1024
#define HID     4
#define BATCH   8192
#define NCOL    (OUT_DIM * HID)   // 4096 = GEMM M dimension (oh), N = 8192 (batch)

typedef __bf16 bf16x8 __attribute__((ext_vector_type(8)));
typedef float  f32x4  __attribute__((ext_vector_type(4)));

__device__ __forceinline__ unsigned short f2bf(float f) {
  union { float f; unsigned int u; } v; v.f = f;
  unsigned int u = v.u;
  u += 0x7FFFu + ((u >> 16) & 1u);   // round-to-nearest-even
  return (unsigned short)(u >> 16);
}

// ---- x: f32 [8192][1024] -> xg bf16 MFMA-B-fragment layout ----
// xg[c4][ko][bl][e]: c4 = batch>>4, ko = k>>3, bl = batch&15, e = k&7.
// One dwordx4 per lane = one 16x16x32 B-fragment; wave reads 1KB contiguous.
__global__ __launch_bounds__(256) void cvt_xg_kernel(const float* __restrict__ x,
                                                     uint4* __restrict__ xg) {
  int g = blockIdx.x * 256 + threadIdx.x;       // granule index (16B)
  int bl = g & 15, ko = (g >> 4) & 127, c4 = g >> 11;
  const float4* xp = (const float4*)(x + (size_t)(c4 * 16 + bl) * 1024 + ko * 8);
  float4 v0 = xp[0], v1 = xp[1];
  uint4 r;
  r.x = f2bf(v0.x) | ((unsigned)f2bf(v0.y) << 16);
  r.y = f2bf(v0.z) | ((unsigned)f2bf(v0.w) << 16);
  r.z = f2bf(v1.x) | ((unsigned)f2bf(v1.y) << 16);
  r.w = f2bf(v1.z) | ((unsigned)f2bf(v1.w) << 16);
  xg[g] = r;                                    // fully coalesced 16B/thread
}

// ---- W1: f32 (O,I,H) -> bf16 W1t[(o*4+h)][i]  (M x K row-major) ----
__global__ __launch_bounds__(256) void cvt_w1t_kernel(const float* __restrict__ W1,
                                                      ushort4* __restrict__ out) {
  int b = blockIdx.x;
  int g = ((b & 7) * ((int)gridDim.x >> 3) + (b >> 3)) * 256 + threadIdx.x;
  int i4 = g & 255;
  int oh = g >> 8;
  int h = oh & 3, o = oh >> 2;
  const float* src = W1 + (size_t)o * 4096 + h;
  ushort4 r;
  r.x = f2bf(src[(i4 * 4 + 0) * 4]);
  r.y = f2bf(src[(i4 * 4 + 1) * 4]);
  r.z = f2bf(src[(i4 * 4 + 2) * 4]);
  r.w = f2bf(src[(i4 * 4 + 3) * 4]);
  out[(size_t)oh * 256 + i4] = r;
}

__device__ __forceinline__ void gload16(const void* g, void* l) {
  __builtin_amdgcn_global_load_lds(
      (const __attribute__((address_space(1))) unsigned int*)g,
      (__attribute__((address_space(3))) unsigned int*)l, 16, 0, 0);
}

// ===== GEMM: C[oh][batch] = W1t x X^T; tile 256(M)x128(N), BK=64 ============
// 4 waves 2(M)x2(N), per-wave 128x64 = acc[8][4] f32x4 (16x16x32 MFMA).
// A via LDS (64 KiB dbuf, gload_lds, R3-proven frow/jq read pattern ~0 confl).
// B DIRECT from L2 (xg fragment layout) into VGPRs - no B LDS round-trip.
// Per-CU block-kt: LDS ~1024 cy < MFMA ~1241 cy -> MFMA-limited; 2 blocks/CU.
__global__ __launch_bounds__(256, 2) void mlp_gemm_kernel(
    const unsigned short* __restrict__ A,   // w1t [4096][1024]  (M = oh)
    const unsigned short* __restrict__ Bg,  // xg fragment layout
    const f32x4* __restrict__ b1v,          // [1024] float4 per o
    const f32x4* __restrict__ w2v,          // [1024] float4 per o
    const float* __restrict__ b2,           // [1024]
    float* __restrict__ out) {              // [8192][1024]
  __shared__ __align__(16) unsigned short lds[32768];   // 64 KiB (A dbuf)

  const int bid = blockIdx.x;                     // 1024 blocks
  const int xcd = bid & 7, loc = bid >> 3;        // 128 blocks per XCD
  const int bn = xcd * 8 + (loc & 7);             // batch tile 0..63 (2MB/XCD L2 slice)
  const int bm = loc >> 3;                        // oh tile 0..15, bn-inner sweep
  const int tileM = bm * 256, tileN = bn * 128;

  const int t = threadIdx.x;
  const int lane = t & 63, wid = t >> 6;
  const int wm = wid >> 1, wn = wid & 1;          // wave -> (oh-half, batch-half)
  const int frow = lane & 15, jq = lane >> 4;

  // ---- A staging: thread t -> rows (t>>3)+32i, 16B slot t&7 (linear dest) ----
  const int sr8 = t >> 3, slt = t & 7;
  const int scol = ((slt ^ (sr8 & 7)) << 3);      // inverse-swizzled source col
  const unsigned short* Asrc = A + (size_t)(tileM + sr8) * IN_DIM + scol;

  auto stage = [&](int kt, int p) {               // 8 x gload16 = 32 KB
    const int kb = kt * 64;
    unsigned short* lA = lds + p * 16384 + t * 8;
#pragma unroll
    for (int i = 0; i < 8; ++i)
      gload16(Asrc + (size_t)(32 * i) * IN_DIM + kb, lA + i * 2048);
  };

  // ---- B direct-load pointers: lane's fragment for (nf, ks) at kt ----
  // byte = ((c4*128 + kt*8 + ks*4 + jq)*16 + frow)*16 ; c4 = tileN/16 + wn*4 + nf
  const int c40 = (tileN >> 4) + wn * 4;
  const char* xgb = (const char*)Bg;
  const char* bp0 = xgb + ((size_t)(c40 * 128 + jq) * 16 + frow) * 16;
  const char* bp1 = bp0 + 32768;                  // nf stride = 128*16*16 B
  const char* bp2 = bp0 + 65536;
  const char* bp3 = bp0 + 98304;

  f32x4 acc[8][4];
#pragma unroll
  for (int m = 0; m < 8; ++m)
#pragma unroll
    for (int n = 0; n < 4; ++n) acc[m][n] = f32x4{0.f, 0.f, 0.f, 0.f};

  // A fragment read constants (R3-proven pattern)
  const int pk0 = (jq ^ (frow & 7)) << 3;         // ks0 swizzled slot (elems)
  const int aRow = (wm * 128 + frow) * 64;        // + mf*1024, + buf*16384

  bf16x8 b0[4], b1_[4];
  stage(0, 0);
  // prologue B(0)
  b0[0] = *(const bf16x8*)(bp0);  b1_[0] = *(const bf16x8*)(bp0 + 1024);
  b0[1] = *(const bf16x8*)(bp1);  b1_[1] = *(const bf16x8*)(bp1 + 1024);
  b0[2] = *(const bf16x8*)(bp2);  b1_[2] = *(const bf16x8*)(bp2 + 1024);
  b0[3] = *(const bf16x8*)(bp3);  b1_[3] = *(const bf16x8*)(bp3 + 1024);
  bp0 += 2048; bp1 += 2048; bp2 += 2048; bp3 += 2048;
  asm volatile("s_waitcnt vmcnt(0)" ::: "memory");
  __builtin_amdgcn_s_barrier();

  for (int kt = 0; kt < 16; ++kt) {
    const int cur = kt & 1;
    if (kt < 15) stage(kt + 1, cur ^ 1);

    const unsigned short* aB = lds + cur * 16384 + aRow;
    bf16x8 a[8];
    // ---- ks = 0 ----
#pragma unroll
    for (int mf = 0; mf < 8; ++mf)
      a[mf] = *(const bf16x8*)(aB + mf * 1024 + pk0);
#pragma unroll
    for (int mf = 0; mf < 8; ++mf) {
      acc[mf][0] = __builtin_amdgcn_mfma_f32_16x16x32_bf16(a[mf], b0[0], acc[mf][0], 0, 0, 0);
      acc[mf][1] = __builtin_amdgcn_mfma_f32_16x16x32_bf16(a[mf], b0[1], acc[mf][1], 0, 0, 0);
      acc[mf][2] = __builtin_amdgcn_mfma_f32_16x16x32_bf16(a[mf], b0[2], acc[mf][2], 0, 0, 0);
      acc[mf][3] = __builtin_amdgcn_mfma_f32_16x16x32_bf16(a[mf], b0[3], acc[mf][3], 0, 0, 0);
    }
    // ---- ks = 1 ----
#pragma unroll
    for (int mf = 0; mf < 8; ++mf)
      a[mf] = *(const bf16x8*)(aB + mf * 1024 + (pk0 ^ 32));
#pragma unroll
    for (int mf = 0; mf < 8; ++mf) {
      acc[mf][0] = __builtin_amdgcn_mfma_f32_16x16x32_bf16(a[mf], b1_[0], acc[mf][0], 0, 0, 0);
      acc[mf][1] = __builtin_amdgcn_mfma_f32_16x16x32_bf16(a[mf], b1_[1], acc[mf][1], 0, 0, 0);
      acc[mf][2] = __builtin_amdgcn_mfma_f32_16x16x32_bf16(a[mf], b1_[2], acc[mf][2], 0, 0, 0);
      acc[mf][3] = __builtin_amdgcn_mfma_f32_16x16x32_bf16(a[mf], b1_[3], acc[mf][3], 0, 0, 0);
    }

    if (kt < 15) {
      asm volatile("s_waitcnt vmcnt(0)" ::: "memory");  // stage(kt+1) landed
      // issue B(kt+1): in flight across the barrier; compiler waits before use
      b0[0] = *(const bf16x8*)(bp0);  b1_[0] = *(const bf16x8*)(bp0 + 1024);
      b0[1] = *(const bf16x8*)(bp1);  b1_[1] = *(const bf16x8*)(bp1 + 1024);
      b0[2] = *(const bf16x8*)(bp2);  b1_[2] = *(const bf16x8*)(bp2 + 1024);
      b0[3] = *(const bf16x8*)(bp3);  b1_[3] = *(const bf16x8*)(bp3 + 1024);
      bp0 += 2048; bp1 += 2048; bp2 += 2048; bp3 += 2048;
      __builtin_amdgcn_s_barrier();
    }
  }
  __syncthreads();   // drain + fence before LDS reuse

  // ---- fused epilogue: in-register hidden-dot ----
  // C/D 16x16: col = frow = batch_local, row16 = jq*4 + j -> h = j,
  // o_loc = wm*32 + mf*4 + jq.
  float* LE = (float*)lds;                        // [128 batch][65] f32 = 33.3 KB
  const int obase = tileM >> 2;                   // block's 64 o-values
#pragma unroll
  for (int mf = 0; mf < 8; ++mf) {
    int o_loc = wm * 32 + mf * 4 + jq;
    f32x4 b1q = b1v[obase + o_loc];
    f32x4 w2q = w2v[obase + o_loc];
#pragma unroll
    for (int nf = 0; nf < 4; ++nf) {
      int bat = wn * 64 + nf * 16 + frow;
      float v = 0.f;
#pragma unroll
      for (int h = 0; h < 4; ++h) {
        float hj = acc[mf][nf][h] + b1q[h];
        hj = (hj >= 0.f) ? hj : 0.1f * hj;        // LeakyReLU(0.1)
        v += hj * w2q[h];
      }
      LE[bat * 65 + o_loc] = v;                   // bank=(bat+o_loc)%32: 2-way
    }
  }
  __syncthreads();

  // coalesced store: out[tileN..+128)[obase..+64)
  const int col = t & 63, rowb = t >> 6;
  const float b2s = b2[obase + col];
  float* outB = out + (size_t)tileN * OUT_DIM + obase;
#pragma unroll
  for (int i = 0; i < 32; ++i) {
    int row = rowb + i * 4;
    outB[(size_t)row * OUT_DIM + col] = LE[row * 65 + col] + b2s;
  }
}

// ---- safety fallback (pure f32, used only if d_ws is too small) ----
__global__ __launch_bounds__(256) void fallback_kernel(
    const float* __restrict__ x, const float* __restrict__ W1,
    const float* __restrict__ b1, const float* __restrict__ W2,
    const float* __restrict__ b2, float* __restrict__ out) {
  int idx = blockIdx.x * 256 + threadIdx.x;
  if (idx >= BATCH * OUT_DIM) return;
  int bb = idx >> 10, o = idx & 1023;
  const float4* w1p = (const float4*)(W1 + (size_t)o * 4096);
  const float*  xp  = x + (size_t)bb * 1024;
  float4 acc = *(const float4*)(b1 + o * 4);
  for (int i = 0; i < 1024; ++i) {
    float xv = xp[i];
    float4 w = w1p[i];
    acc.x += xv * w.x; acc.y += xv * w.y; acc.z += xv * w.z; acc.w += xv * w.w;
  }
  float4 w2 = *(const float4*)(W2 + o * 4);
  float r = b2[o];
  r += ((acc.x >= 0.f) ? acc.x : 0.1f * acc.x) * w2.x;
  r += ((acc.y >= 0.f) ? acc.y : 0.1f * acc.y) * w2.y;
  r += ((acc.z >= 0.f) ? acc.z : 0.1f * acc.z) * w2.z;
  r += ((acc.w >= 0.f) ? acc.w : 0.1f * acc.w) * w2.w;
  out[(size_t)bb * OUT_DIM + o] = r;
}

extern "C" void kernel_launch(void* const* d_in, const int* in_sizes, int n_in,
                              void* d_out, int out_size, void* d_ws, size_t ws_size,
                              hipStream_t stream) {
  const float* x  = (const float*)d_in[0];
  const float* W1 = (const float*)d_in[1];
  const float* b1 = (const float*)d_in[2];
  const float* W2 = (const float*)d_in[3];
  const float* b2 = (const float*)d_in[4];
  float* out = (float*)d_out;

  size_t need = (size_t)BATCH * IN_DIM * 2 + (size_t)NCOL * IN_DIM * 2;  // 25.2 MB
  if (ws_size >= need) {
    unsigned short* xg  = (unsigned short*)d_ws;
    unsigned short* w1t = xg + (size_t)BATCH * IN_DIM;
    cvt_xg_kernel<<<(BATCH * IN_DIM / 8) / 256, 256, 0, stream>>>(x, (uint4*)xg);
    cvt_w1t_kernel<<<(NCOL * IN_DIM / 4) / 256, 256, 0, stream>>>(W1, (ushort4*)w1t);
    mlp_gemm_kernel<<<(NCOL / 256) * (BATCH / 128), 256, 0, stream>>>(
        w1t, xg, (const f32x4*)b1, (const f32x4*)W2, b2, out);
  } else {
    fallback_kernel<<<(BATCH * OUT_DIM + 255) / 256, 256, 0, stream>>>(x, W1, b1, W2, b2, out);
  }
}